// Round 9
// baseline (274.569 us; speedup 1.0000x reference)
//
#include <hip/hip_runtime.h>
#include <cstdint>

// Problem constants
#define LSEQ 1024
#define BATCH 16
#define NIN 1024
#define NOUT 512
#define KGATE 5
#define NCOL (NOUT * KGATE)           // 2560
#define MTOT (LSEQ * BATCH)           // 16384
#define CHAINS (BATCH * NOUT)         // 8192
#define OUT_GCS (LSEQ * BATCH * NOUT) // 8388608
#define SEG 32                        // segments
#define SLEN 32                       // steps per segment
#define PLANE ((size_t)MTOT * NOUT)   // elements per gate plane (8M)
#define SMP ((size_t)SEG * CHAINS)    // elements per segmap plane (256K)

// GEMM geometry: 3-slot counted-vmcnt pipeline (T4), 2-ahead staging
#define BM 256
#define BN 128
#define BK 32
#define NT (NIN / BK)                 // 32 K-tiles
#define SLOTB 24576                   // bytes per LDS slot (A 16K + B 8K)

// Scan-kernel tiling: per block = 1 segment x 256 chains, staged in LDS
#define CGRP 256                      // chains per block
#define JPH 8                         // steps per staged phase (4 phases = SLEN)

typedef _Float16 f16x8 __attribute__((ext_vector_type(8)));
typedef _Float16 f16x4 __attribute__((ext_vector_type(4)));
typedef float f32x4 __attribute__((ext_vector_type(4)));

__device__ __forceinline__ void async16(const void* g, void* l) {
    __builtin_amdgcn_global_load_lds(
        (const __attribute__((address_space(1))) void*)(uintptr_t)g,
        (__attribute__((address_space(3))) void*)(uintptr_t)l,
        16, 0, 0);
}

__device__ __forceinline__ float fsigmoid(float x) {
    return 1.0f / (1.0f + __expf(-x));
}

// ---------------- Kernel 1: convert x fp32 -> f16 (8 elems/thread) ----------------
__global__ void convert_x_k(const float* __restrict__ x, _Float16* __restrict__ xb, int n8) {
    int i = blockIdx.x * blockDim.x + threadIdx.x;
    if (i < n8) {
        float4 a = ((const float4*)x)[2 * i];
        float4 b = ((const float4*)x)[2 * i + 1];
        f16x8 h;
        h[0] = (_Float16)a.x; h[1] = (_Float16)a.y; h[2] = (_Float16)a.z; h[3] = (_Float16)a.w;
        h[4] = (_Float16)b.x; h[5] = (_Float16)b.y; h[6] = (_Float16)b.z; h[7] = (_Float16)b.w;
        ((f16x8*)xb)[i] = h;
    }
}

// ---------------- Kernel 2: transpose+convert+PERMUTE weight ----------------
// w [1024][2560] f32 -> wT [2560][1024] f16; orig col c=n*5+g -> row' = g*512+n
__global__ __launch_bounds__(256) void transpose_w_k(const float* __restrict__ w, _Float16* __restrict__ wT) {
    __shared__ float lds[32][33];
    int t = threadIdx.x;
    int col = t & 31;
    int rowg = t >> 5;
    int n0 = blockIdx.x * 32;
    int k0 = blockIdx.y * 32;
#pragma unroll
    for (int i = 0; i < 4; i++) {
        int r = rowg + i * 8;
        lds[r][col] = w[(size_t)(k0 + r) * NCOL + n0 + col];
    }
    __syncthreads();
#pragma unroll
    for (int i = 0; i < 4; i++) {
        int r = rowg + i * 8;
        int c = n0 + r;
        int row = (c % 5) * NOUT + (c / 5);
        wT[(size_t)row * NIN + k0 + col] = (_Float16)lds[col][r];
    }
}

// ---------------- Kernel 3: MFMA GEMM 256x128, BK=32, 3-slot counted-vmcnt pipeline ------
// A: xb [16384][1024] f16; BT: wT [2560][1024] f16 (gate-plane-permuted cols)
// Round-8's 1-ahead + __syncthreads drains vmcnt(0) every tile: each tile's
// staging must land within its own compute window -> MfmaUtil capped ~25-33%.
// T4 fix: 3 LDS slots (72 KB, 2 blocks/CU), stage tile t+2 at top of tile t,
// end tile with s_waitcnt vmcnt(6) (only tile t+1 must land; t+2's 6 loads stay
// in flight ACROSS the barrier) + raw s_barrier + sched_barrier(0) (rule 18:
// pin next tile's ds_reads below the barrier). Hazards audited:
//   WAR: stage(t+2) -> slot (t-1)%3; its readers' ds_reads all fed MFMAs before
//        the end-of-(t-1) barrier, and staging issues only after that barrier.
//   RAW: own-wave vmcnt + barrier covers cross-wave gload_lds writes.
// LDS swizzle / staging maps / epilogue identical to the verified round-8 kernel.
__global__ __launch_bounds__(256, 2) void gemm_gates_k(const _Float16* __restrict__ A,
                                                       const _Float16* __restrict__ BT,
                                                       const float* __restrict__ bias,
                                                       _Float16* __restrict__ planes) {
    // 72 KiB: slot s at byte s*24576; A tile [256][32] at +0, B tile [128][32] at +16384
    __shared__ _Float16 lds[36864];
    const int t = threadIdx.x;
    const int w = t >> 6, lane = t & 63;
    const int q = lane >> 4, r16 = lane & 15;
    const int wm = (w >> 1) * 128, wn = (w & 1) * 64;
    const int m0 = blockIdx.x * BM, n0 = blockIdx.y * BN;

    // Within-slot read bases (row*64B + swizzled 16B chunk).
    const int swz = (q ^ ((r16 >> 1) & 3)) << 4;
    const int aBase = (wm + r16) * 64 + swz;            // + i*1024 + slot*SLOTB
    const int bBase = 16384 + (wn + r16) * 64 + swz;    // + j*1024 + slot*SLOTB

    // Staging maps (identical to round 8, verified): rS = t>>2, chunk swizzle
    // lane-constant across L (rows step by 64).
    const int rS = t >> 2;
    const int skS = (t & 3) ^ ((rS >> 1) & 3);
    const _Float16* aS = A + (size_t)(m0 + rS) * NIN + skS * 8;
    const _Float16* bS = BT + (size_t)(n0 + rS) * NIN + skS * 8;
    char* const ldsb = (char*)lds;
    const int dstT = t * 16;             // + L*4096 (+16384 for B)

    auto stage = [&](int tile, int slot) {
        const _Float16* ap = aS + (size_t)tile * BK;
        const _Float16* bp = bS + (size_t)tile * BK;
        char* base = ldsb + slot * SLOTB;
#pragma unroll
        for (int L = 0; L < 4; L++)
            async16(ap + (size_t)L * 64 * NIN, base + dstT + L * 4096);
#pragma unroll
        for (int L = 0; L < 2; L++)
            async16(bp + (size_t)L * 64 * NIN, base + 16384 + dstT + L * 4096);
    };

    f32x4 acc[8][4] = {};

    // Prologue: tiles 0,1 in flight; wait for tile 0 (oldest 6 of 12), barrier.
    stage(0, 0);
    stage(1, 1);
    asm volatile("s_waitcnt vmcnt(6)" ::: "memory");
    __builtin_amdgcn_s_barrier();
    __builtin_amdgcn_sched_barrier(0);

    int cs = 0;        // slot of current tile (tt % 3)
    int ssl = 2;       // slot for stage(tt+2)
#pragma unroll 2
    for (int tt = 0; tt < NT; tt++) {
        if (tt + 2 < NT) stage(tt + 2, ssl);

        f16x8 af[8], bf[4];
        const char* ab = ldsb + cs * SLOTB + aBase;
        const char* bb = ldsb + cs * SLOTB + bBase;
#pragma unroll
        for (int i = 0; i < 8; i++) af[i] = *(const f16x8*)(ab + i * 1024);
#pragma unroll
        for (int j = 0; j < 4; j++) bf[j] = *(const f16x8*)(bb + j * 1024);

        __builtin_amdgcn_s_setprio(1);
#pragma unroll
        for (int i = 0; i < 8; i++)
#pragma unroll
            for (int j = 0; j < 4; j++)
                acc[i][j] = __builtin_amdgcn_mfma_f32_16x16x32_f16(bf[j], af[i], acc[i][j], 0, 0, 0);
        __builtin_amdgcn_s_setprio(0);

        if (tt + 1 < NT) {
            if (tt + 2 < NT) {
                asm volatile("s_waitcnt vmcnt(6)" ::: "memory");  // tile tt+1 landed; tt+2 stays in flight
            } else {
                asm volatile("s_waitcnt vmcnt(0)" ::: "memory");  // tail: drain tile tt+1
            }
            __builtin_amdgcn_s_barrier();
            __builtin_amdgcn_sched_barrier(0);
        }
        cs = (cs == 2) ? 0 : cs + 1;
        ssl = (ssl == 2) ? 0 : ssl + 1;
    }

    // Epilogue: acc[i][j] = C^T frag: m = wm + i*16 + r16, n = wn + j*16 + q*4 + reg
    const int g = n0 >> 9;
    const int nb = n0 & (NOUT - 1);
    _Float16* plane = planes + (size_t)g * PLANE;
#pragma unroll
    for (int i = 0; i < 8; i++) {
        int m = m0 + wm + i * 16 + r16;
        _Float16* prow = plane + (size_t)m * NOUT + nb;
#pragma unroll
        for (int j = 0; j < 4; j++) {
            int nn = wn + j * 16 + q * 4;
            float4 bv = *(const float4*)(bias + n0 + nn);
            f16x4 hv;
#pragma unroll
            for (int reg = 0; reg < 4; reg++) {
                float v = acc[i][j][reg];
                float b = (reg == 0) ? bv.x : (reg == 1) ? bv.y : (reg == 2) ? bv.z : bv.w;
                if (g >= 2) v = fsigmoid(v + b);
                hv[reg] = (_Float16)v;
            }
            *(f16x4*)(prow + nn) = hv;
        }
    }
}

// ---------------- Kernel 4a: compose per-segment affine maps (reg-staged LDS) ----------------
// (byte-identical to round 8 passing version)
// Buffer schedule: buf0:{ph0,ph2}, buf1:{ph1,ph3} -> compute calls (0),(1),(0),(1).
__global__ __launch_bounds__(256) void compose_k(const _Float16* __restrict__ planes,
                                                 const float* __restrict__ beps,
                                                 float* __restrict__ SM) {
    __shared__ _Float16 tile[2][4][JPH][CGRP];   // 32 KB
    const int t = threadIdx.x;
    const int s = blockIdx.x >> 5;               // segment
    const int grp = blockIdx.x & 31;             // chain group
    const int tch = grp * CGRP + t;
    const int n = tch & (NOUT - 1);
    const int jl = t >> 5, ci = t & 31;

    auto stage = [&](int ph, int b) {
        const int j0 = s * SLEN + ph * JPH;
        f16x8 v[4];
#pragma unroll
        for (int r = 0; r < 4; r++)
            v[r] = *(const f16x8*)(planes + (size_t)r * PLANE + (size_t)(j0 + jl) * CHAINS + grp * CGRP + ci * 8);
#pragma unroll
        for (int r = 0; r < 4; r++)
            *(f16x8*)((char*)tile + b * 16384 + (t + r * 256) * 16) = v[r];
    };

    float eps = fsigmoid(beps[n]);
    float a11 = 1.0f, a21 = 0.0f, a22 = 1.0f, b1 = 0.0f, b2 = 0.0f;

    auto computeph = [&](int b) {
#pragma unroll
        for (int j = 0; j < JPH; j++) {
            float u1 = (float)tile[b][0][j][t];
            float u2 = (float)tile[b][1][j][t];
            float f1 = (float)tile[b][2][j][t];
            float f2 = (float)tile[b][3][j][t];
            float na11 = f1 * a11;
            float na21 = fmaf(u2, a11, f2 * a21);
            float na22 = f2 * a22;
            float nb1  = fmaf(f1, b1, u1);
            float nb2  = fmaf(u2, b1, fmaf(f2, b2, eps * u2));
            a11 = na11; a21 = na21; a22 = na22; b1 = nb1; b2 = nb2;
        }
    };

    stage(0, 0);
    stage(1, 1);
    __syncthreads();       // buf0+buf1 visible to every wave
    computeph(0);          // phase 0 from buf 0
    __syncthreads();       // all waves done reading buf 0
    stage(2, 0);
    __syncthreads();       // buf 0 = phase 2
    computeph(1);          // phase 1 from buf 1
    __syncthreads();       // all waves done reading buf 1
    stage(3, 1);
    __syncthreads();       // buf 1 = phase 3
    computeph(0);          // phase 2 from buf 0
    computeph(1);          // phase 3 from buf 1

    size_t idx = (size_t)s * CHAINS + tch;
    SM[idx]           = a11;
    SM[SMP + idx]     = a21;
    SM[2 * SMP + idx] = a22;
    SM[3 * SMP + idx] = b1;
    SM[4 * SMP + idx] = b2;
}

// ---------------- Kernel 4b: sequential scan over segment maps (prefetched) ----------------
__global__ __launch_bounds__(256) void segscan_k(const float* __restrict__ SM,
                                                 float* __restrict__ segc,
                                                 float* __restrict__ out) {
    int t = blockIdx.x * 256 + threadIdx.x;  // 0..8191
    float c1 = 0.0f, c2 = 0.0f;
    float a11n = SM[t], a21n = SM[SMP + t], a22n = SM[2 * SMP + t];
    float b1n = SM[3 * SMP + t], b2n = SM[4 * SMP + t];
#pragma unroll
    for (int s = 0; s < SEG; s++) {
        float a11 = a11n, a21 = a21n, a22 = a22n, b1 = b1n, b2 = b2n;
        if (s + 1 < SEG) {
            size_t nx = (size_t)(s + 1) * CHAINS + t;
            a11n = SM[nx]; a21n = SM[SMP + nx]; a22n = SM[2 * SMP + nx];
            b1n = SM[3 * SMP + nx]; b2n = SM[4 * SMP + nx];
        }
        size_t idx = (size_t)s * CHAINS + t;
        segc[idx] = c1;
        segc[SMP + idx] = c2;
        float c1n = fmaf(a11, c1, b1);
        float c2n = fmaf(a21, c1, fmaf(a22, c2, b2));
        c1 = c1n; c2 = c2n;
    }
    out[OUT_GCS + t] = c1;
    out[OUT_GCS + CHAINS + t] = c2;
}

// ---------------- Kernel 4c: apply within segments + fused output (reg-staged LDS) ----------
// (byte-identical to round 8 passing version)
__global__ __launch_bounds__(256) void apply_k(const _Float16* __restrict__ planes,
                                               const float* __restrict__ segc,
                                               const float* __restrict__ beps,
                                               const float* __restrict__ bfin,
                                               float* __restrict__ out) {
    __shared__ _Float16 tile[2][5][JPH][CGRP];   // 40 KB
    const int t = threadIdx.x;
    const int s = blockIdx.x >> 5;
    const int grp = blockIdx.x & 31;
    const int tch = grp * CGRP + t;
    const int n = tch & (NOUT - 1);
    const int jl = t >> 5, ci = t & 31;

    auto stage = [&](int ph, int b) {
        const int j0 = s * SLEN + ph * JPH;
        f16x8 v[5];
#pragma unroll
        for (int r = 0; r < 5; r++)
            v[r] = *(const f16x8*)(planes + (size_t)r * PLANE + (size_t)(j0 + jl) * CHAINS + grp * CGRP + ci * 8);
#pragma unroll
        for (int r = 0; r < 5; r++)
            *(f16x8*)((char*)tile + b * 20480 + (t + r * 256) * 16) = v[r];
    };

    size_t idx = (size_t)s * CHAINS + tch;
    float c1 = segc[idx];
    float c2 = segc[SMP + idx];
    float eps  = fsigmoid(beps[n]);
    float rho0 = 2.0f * fsigmoid(bfin[2 * n]);
    float rho1 = 2.0f * fsigmoid(bfin[2 * n + 1]);

    auto computeph = [&](int ph, int b) {
        size_t eo = (size_t)(s * SLEN + ph * JPH) * CHAINS + tch;
#pragma unroll
        for (int j = 0; j < JPH; j++) {
            float u1 = (float)tile[b][0][j][t];
            float u2 = (float)tile[b][1][j][t];
            float f1 = (float)tile[b][2][j][t];
            float f2 = (float)tile[b][3][j][t];
            float o  = (float)tile[b][4][j][t];
            float c1p = c1;
            c1 = fmaf(c1p, f1, u1);
            c2 = fmaf(c2, f2, (eps + c1p) * u2);
            float cs = fmaf(c1, rho0, c2 * rho1);
            float y = o * cs;
            y = fminf(9.0f, fmaxf(-9.0f, y));
            float ex = __expf(2.0f * y);
            out[eo] = (ex - 1.0f) / (ex + 1.0f);   // tanh(y)
            eo += CHAINS;
        }
    };

    stage(0, 0);
    stage(1, 1);
    __syncthreads();       // buf0+buf1 visible
    computeph(0, 0);
    __syncthreads();       // all waves done reading buf 0
    stage(2, 0);
    __syncthreads();       // buf 0 = phase 2
    computeph(1, 1);
    __syncthreads();       // all waves done reading buf 1
    stage(3, 1);
    __syncthreads();       // buf 1 = phase 3
    computeph(2, 0);
    computeph(3, 1);
}

extern "C" void kernel_launch(void* const* d_in, const int* in_sizes, int n_in,
                              void* d_out, int out_size, void* d_ws, size_t ws_size,
                              hipStream_t stream) {
    const float* x    = (const float*)d_in[0];
    const float* wgt  = (const float*)d_in[1];
    const float* bias = (const float*)d_in[2];
    const float* beps = (const float*)d_in[3];
    const float* bfin = (const float*)d_in[4];
    float* out = (float*)d_out;

    // Workspace layout (~124 MB)
    char* p = (char*)d_ws;
    _Float16* wT     = (_Float16*)p; p += (size_t)NCOL * NIN * 2;        // 5 MB
    _Float16* xb     = (_Float16*)p; p += (size_t)MTOT * NIN * 2;        // 32 MB
    _Float16* planes = (_Float16*)p; p += 5 * PLANE * 2;                 // 80 MB
    float* SM        = (float*)p;    p += 5 * SMP * 4;                   // 5 MB
    float* segc      = (float*)p;    p += 2 * SMP * 4;                   // 2 MB

    transpose_w_k<<<dim3(NCOL / 32, NIN / 32), 256, 0, stream>>>(wgt, wT);

    int n8 = MTOT * NIN / 8;
    convert_x_k<<<dim3((n8 + 255) / 256), 256, 0, stream>>>(x, xb, n8);

    gemm_gates_k<<<dim3(MTOT / BM, NCOL / BN), 256, 0, stream>>>(xb, wT, bias, planes);

    compose_k<<<dim3(SEG * (CHAINS / CGRP)), 256, 0, stream>>>(planes, beps, SM);
    segscan_k<<<dim3(CHAINS / 256), 256, 0, stream>>>(SM, segc, out);
    apply_k<<<dim3(SEG * (CHAINS / CGRP)), 256, 0, stream>>>(planes, segc, beps, bfin, out);
}